// Round 10
// baseline (85.326 us; speedup 1.0000x reference)
//
#include <hip/hip_runtime.h>
#include <hip/hip_bf16.h>

typedef unsigned short u16;
typedef unsigned int   u32;
typedef unsigned long long u64;
typedef __attribute__((ext_vector_type(8)))  __bf16 bf16x8;
typedef __attribute__((ext_vector_type(4)))  float  f32x4;
typedef __attribute__((ext_vector_type(16))) float  f32x16;
typedef __attribute__((ext_vector_type(8)))  u16    ushort8;
typedef __attribute__((ext_vector_type(4)))  u32    u32x4;

#define S_LEN 2048
#define D_DIM 64
#define NBH   32
#define SD    131072
#define MROW  32
#define MB_PB 65536
#define NT    32            // KV tiles of 64

// Fragment-linear buffers: per (bh, tile): 512 frags x 16B = 8KB.
// K frag f = s*128 + T*64 + l  -> K[tile*64 + T*32 + (l&31)][s*16 + (l>>5)*8 + 0..7]
// V frag f = ks*128 + D0*64 + l -> V[tile*64 + ks*16 + (l>>5)*8 + j][D0*32 + (l&31)]
#define FR_BH 131072        // u16 per bh (32 tiles * 4096)

// workspace layout (bytes): Kf 8MB | Vf 8MB | Mb 1MB | pad
#define KF_OFF 0u
#define VF_OFF 8388608u
#define MB_OFF 16777216u
#define WS_NEED 17833984u

#define QSCALE 0.18033688011112042f   // 0.125 * log2(e) -> scores in log2 domain

static __device__ __forceinline__ u16 f2bf(float f) {
  u32 u = __builtin_bit_cast(u32, f);
  u += 0x7fffu + ((u >> 16) & 1u);
  return (u16)(u >> 16);
}

static __device__ __forceinline__ void gl16(const void* g, void* l) {
  __builtin_amdgcn_global_load_lds(
      (const __attribute__((address_space(1))) u32*)g,
      (__attribute__((address_space(3))) u32*)l, 16, 0, 0);
}

static __device__ __forceinline__ u32 cvtpk(float lo, float hi) {
  u32 d;
  asm("v_cvt_pk_bf16_f32 %0, %1, %2" : "=v"(d) : "v"(lo), "v"(hi));
  return d;
}
// ONLY safe when a and b are distinct SSA values (regalloc may alias equal
// values to one VGPR -> in-place half-swap). Equal-value exchange: __shfl_xor.
static __device__ __forceinline__ void plswap(u32& a, u32& b) {
  asm volatile("v_permlane32_swap_b32 %0, %1" : "+v"(a), "+v"(b));
}

#define WAITV0 asm volatile("s_waitcnt vmcnt(0)" ::: "memory")

// ---------------- fused prep kernel ----------------
__global__ __launch_bounds__(256) void prep_all(
    const float* __restrict__ K, const float* __restrict__ V, const int* __restrict__ M,
    u16* __restrict__ Kf, u16* __restrict__ Vf, u64* __restrict__ Mb) {
  const int bx = blockIdx.x, tid = threadIdx.x;
  if (bx < 2048) {
    __shared__ u16 t[64][72];
    const bool isK = bx < 1024;
    const int idx = isK ? bx : bx - 1024;
    const int bh = idx >> 5, tt = idx & 31;
    const float* src = (isK ? K : V) + ((size_t)bh * S_LEN + tt * 64) * D_DIM;
    const int r = tid >> 2, c0 = (tid & 3) * 16;
#pragma unroll
    for (int i = 0; i < 16; i += 4) {
      float4 x = *reinterpret_cast<const float4*>(src + r * 64 + c0 + i);
      t[r][c0+i]   = f2bf(x.x); t[r][c0+i+1] = f2bf(x.y);
      t[r][c0+i+2] = f2bf(x.z); t[r][c0+i+3] = f2bf(x.w);
    }
    __syncthreads();
    u16* dst = (isK ? Kf : Vf) + (size_t)bh * FR_BH + (size_t)tt * 4096;
#pragma unroll
    for (int qq = 0; qq < 2; ++qq) {
      const int f = tid * 2 + qq;
      const int sp = f >> 7, half = (f >> 6) & 1, l = f & 63;
      ushort8 u;
      if (isK) {
        u = *reinterpret_cast<const ushort8*>(&t[half * 32 + (l & 31)][sp * 16 + (l >> 5) * 8]);
      } else {
        const int kv0 = sp * 16 + (l >> 5) * 8, d = half * 32 + (l & 31);
#pragma unroll
        for (int j = 0; j < 8; ++j) u[j] = t[kv0 + j][d];
      }
      *reinterpret_cast<ushort8*>(dst + (size_t)f * 8) = u;
    }
  } else {
    int g = (bx - 2048) * 256 + tid;
    int lane = g & 63;
    int v = M[(size_t)g];
    u64 bits = __ballot(v != 0);
    if (lane == 0) Mb[g >> 6] = bits;
  }
}

// ---------------- main kernel (v10): intra-block KV-split, 16 waves/CU ----------------
// 512 thr = 8 waves = 4 q-positions x 2 KV-half groups. No-max softmax makes
// partials ADDITIVE (O=SUM O_g, l=SUM l_g) -> merge via one LDS exchange.
// Per group: DEPTH=2 double-buffered fragment-linear staging (conflict-free
// ds_read_b128 at base+lane*16), distance-1 prefetch, WAITV0+s_barrier per iter.
static __device__ __forceinline__ void iter_body(
    const u16* kb, const u16* vb, u64 mw,
    const bf16x8* Qf, f32x16& accOT0, f32x16& accOT1, float& l_,
    int lane, int hi) {
  const u32 mlo = (u32)mw, mhiw = (u32)(mw >> 32);

  // ---- QK^T (swapped): sT = K[tile] x Q^T, D[kv][q] ----
  f32x16 sT0 = {0,0,0,0,0,0,0,0,0,0,0,0,0,0,0,0};
  f32x16 sT1 = {0,0,0,0,0,0,0,0,0,0,0,0,0,0,0,0};
  __builtin_amdgcn_s_setprio(1);
#pragma unroll
  for (int s = 0; s < 4; ++s) {
    bf16x8 k0 = *reinterpret_cast<const bf16x8*>(kb + s * 1024 + lane * 8);
    bf16x8 k1 = *reinterpret_cast<const bf16x8*>(kb + s * 1024 + 512 + lane * 8);
    sT0 = __builtin_amdgcn_mfma_f32_32x32x16_bf16(k0, Qf[s], sT0, 0, 0, 0);
    sT1 = __builtin_amdgcn_mfma_f32_32x32x16_bf16(k1, Qf[s], sT1, 0, 0, 0);
  }
  __builtin_amdgcn_s_setprio(0);

  // ---- p = exp2(s), mask via sbfe+and, sum, pack to bf16 ----
  float lp0 = 0.f, lp1 = 0.f;
  u32 A0_[8], A1_[8];
#pragma unroll
  for (int T = 0; T < 2; ++T) {
    const f32x16& sv = T ? sT1 : sT0;
    const u32 mword = T ? mhiw : mlo;
#pragma unroll
    for (int j = 0; j < 8; ++j) {
      const int r0 = 2 * j, r1 = 2 * j + 1;
      const int b0 = (r0 & 3) + 8 * (r0 >> 2) + 4 * hi;
      const int b1 = (r1 & 3) + 8 * (r1 >> 2) + 4 * hi;
      float e0 = __builtin_amdgcn_exp2f(sv[r0]);
      float e1 = __builtin_amdgcn_exp2f(sv[r1]);
      int s0 = __builtin_amdgcn_sbfe(mword, b0, 1);
      int s1 = __builtin_amdgcn_sbfe(mword, b1, 1);
      e0 = __builtin_bit_cast(float, __builtin_bit_cast(u32, e0) & (u32)s0);
      e1 = __builtin_bit_cast(float, __builtin_bit_cast(u32, e1) & (u32)s1);
      lp0 += e0; lp1 += e1;
      u32 w = cvtpk(e0, e1);
      if (T == 0) A0_[j] = w; else A1_[j] = w;
    }
  }
  l_ += lp0 + lp1;

  // ---- build PV B-fragments in-register (distinct-operand permlane swaps) ----
  bf16x8 PA[4];
  {
    u32 a, c, b2, d2;
    a = A0_[0]; c = A0_[2]; plswap(a, c);
    b2 = A0_[1]; d2 = A0_[3]; plswap(b2, d2);
    u32x4 w0 = {a, b2, c, d2}; PA[0] = __builtin_bit_cast(bf16x8, w0);
    a = A0_[4]; c = A0_[6]; plswap(a, c);
    b2 = A0_[5]; d2 = A0_[7]; plswap(b2, d2);
    u32x4 w1 = {a, b2, c, d2}; PA[1] = __builtin_bit_cast(bf16x8, w1);
    a = A1_[0]; c = A1_[2]; plswap(a, c);
    b2 = A1_[1]; d2 = A1_[3]; plswap(b2, d2);
    u32x4 w2 = {a, b2, c, d2}; PA[2] = __builtin_bit_cast(bf16x8, w2);
    a = A1_[4]; c = A1_[6]; plswap(a, c);
    b2 = A1_[5]; d2 = A1_[7]; plswap(b2, d2);
    u32x4 w3 = {a, b2, c, d2}; PA[3] = __builtin_bit_cast(bf16x8, w3);
  }

  // ---- PV (swapped): accOT[D0] += V^T[D0-tile] x P^T ----
  __builtin_amdgcn_s_setprio(1);
#pragma unroll
  for (int ks = 0; ks < 4; ++ks) {
    bf16x8 v0 = *reinterpret_cast<const bf16x8*>(vb + ks * 1024 + lane * 8);
    bf16x8 v1 = *reinterpret_cast<const bf16x8*>(vb + ks * 1024 + 512 + lane * 8);
    accOT0 = __builtin_amdgcn_mfma_f32_32x32x16_bf16(v0, PA[ks], accOT0, 0, 0, 0);
    accOT1 = __builtin_amdgcn_mfma_f32_32x32x16_bf16(v1, PA[ks], accOT1, 0, 0, 0);
  }
  __builtin_amdgcn_s_setprio(0);
}

__global__ __launch_bounds__(512, 4) void attn_fwd10(
    const float* __restrict__ Q, const u16* __restrict__ Kf,
    const u16* __restrict__ Vf, const u64* __restrict__ Mb,
    float* __restrict__ O) {
  __shared__ __align__(16) u16 LB[32768];   // 64KB: per group 16384 u16 (K 2x4096 | V 2x4096)

  const int tid  = threadIdx.x;
  const int lane = tid & 63;
  const int wid  = tid >> 6;       // 0..7
  const int grp  = wid >> 2;       // KV-half group
  const int gw   = wid & 3;        // q-position within block
  const int l31  = lane & 31;
  const int hi   = lane >> 5;
  const int ts   = tid & 255;      // thread index within group

  const int bh = blockIdx.y, b = bh >> 4;
  const int q0w = blockIdx.x * 128 + gw * 32;
  const size_t base = (size_t)bh * SD;

  // Q fragments: f32 load + scale + pack (both groups load same rows)
  bf16x8 Qf[4];
  {
    const float* qsrc = Q + base + (size_t)(q0w + l31) * 64;
#pragma unroll
    for (int s = 0; s < 4; ++s) {
      const int d0 = s * 16 + hi * 8;
      float4 x = *reinterpret_cast<const float4*>(qsrc + d0);
      float4 y = *reinterpret_cast<const float4*>(qsrc + d0 + 4);
      u32x4 w;
      w[0] = cvtpk(x.x * QSCALE, x.y * QSCALE);
      w[1] = cvtpk(x.z * QSCALE, x.w * QSCALE);
      w[2] = cvtpk(y.x * QSCALE, y.y * QSCALE);
      w[3] = cvtpk(y.z * QSCALE, y.w * QSCALE);
      Qf[s] = __builtin_bit_cast(bf16x8, w);
    }
  }

  u16* gK = LB + grp * 16384;          // group K bufs [2][4096] u16
  u16* gV = gK + 8192;                 // group V bufs [2][4096] u16

  const u16* kfA = Kf + (size_t)bh * FR_BH;
  const u16* vfA = Vf + (size_t)bh * FR_BH;
  const u64* mp  = Mb + (size_t)b * MB_PB + (size_t)(q0w + l31) * MROW;

  f32x16 accOT0 = {0,0,0,0,0,0,0,0,0,0,0,0,0,0,0,0};
  f32x16 accOT1 = {0,0,0,0,0,0,0,0,0,0,0,0,0,0,0,0};
  float l_ = 0.f;

#define STAGE(buf, tile) do {                                                      \
    gl16(kfA + (size_t)(tile) * 4096 + ts * 8,        gK + (buf) * 4096 + ts * 8); \
    gl16(kfA + (size_t)(tile) * 4096 + 2048 + ts * 8, gK + (buf) * 4096 + 2048 + ts * 8); \
    gl16(vfA + (size_t)(tile) * 4096 + ts * 8,        gV + (buf) * 4096 + ts * 8); \
    gl16(vfA + (size_t)(tile) * 4096 + 2048 + ts * 8, gV + (buf) * 4096 + 2048 + ts * 8); \
  } while (0)

  const int t0 = grp * 16;
  STAGE(0, t0);
  u64 cmCur = mp[t0];
  WAITV0;
  __builtin_amdgcn_s_barrier();

  int buf = 0;
#pragma unroll 1
  for (int it = 0; it < 16; ++it) {
    u64 cmNext = 0;
    if (it < 15) {                       // prefetch next tile into other buffer
      STAGE(buf ^ 1, t0 + it + 1);       // (overwrites buffer freed by prev barrier)
      cmNext = mp[t0 + it + 1];
    }
    iter_body(gK + buf * 4096, gV + buf * 4096, cmCur,
              Qf, accOT0, accOT1, l_, lane, hi);
    cmCur = cmNext;
    WAITV0;                              // own-wave stage loads landed (had full compute to fly)
    __builtin_amdgcn_s_barrier();        // all waves done: buffers swappable
    buf ^= 1;
  }

  // ---- merge the two KV-half partials (pure sums: no-max softmax is additive) ----
  l_ += __shfl_xor(l_, 32);
  __syncthreads();
  float* P = (float*)((char*)LB + 24576);          // [256 threads][34] f32 (34KB region)
  const int pidx = (gw * 64 + lane) * 34;
  if (grp == 1) {
#pragma unroll
    for (int r = 0; r < 16; ++r) P[pidx + r]      = accOT0[r];
#pragma unroll
    for (int r = 0; r < 16; ++r) P[pidx + 16 + r] = accOT1[r];
    P[pidx + 32] = l_;
  }
  __syncthreads();
  if (grp == 0) {
#pragma unroll
    for (int r = 0; r < 16; ++r) accOT0[r] += P[pidx + r];
#pragma unroll
    for (int r = 0; r < 16; ++r) accOT1[r] += P[pidx + 16 + r];
    l_ += P[pidx + 32];

    const float inv = __builtin_amdgcn_rcpf(l_);
    float* sc = (float*)((char*)LB + gw * 4608);   // per-wave [32][36] f32 bounce
#pragma unroll
    for (int D0 = 0; D0 < 2; ++D0) {
      const f32x16& acc = D0 ? accOT1 : accOT0;
#pragma unroll
      for (int r = 0; r < 16; ++r) {
        const int dloc = (r & 3) + 8 * (r >> 2) + 4 * hi;
        sc[l31 * 36 + dloc] = acc[r] * inv;
      }
      asm volatile("s_waitcnt lgkmcnt(0)" ::: "memory");
      __builtin_amdgcn_sched_barrier(0);
      const int qq = lane >> 1, off = (lane & 1) * 16;
#pragma unroll
      for (int j = 0; j < 4; ++j) {
        float4 x = *reinterpret_cast<const float4*>(&sc[qq * 36 + off + j * 4]);
        *reinterpret_cast<float4*>(O + base + (size_t)(q0w + qq) * 64 + D0 * 32 + off + j * 4) = x;
      }
      asm volatile("s_waitcnt lgkmcnt(0)" ::: "memory");
      __builtin_amdgcn_sched_barrier(0);
    }
  }
#undef STAGE
}

// ---------------- fallback (round-1 kernel, used if ws too small) ----------------
#define KST 72
#define VST 40
#define PST 40
static __device__ __forceinline__ bf16x8 ld_frag(const u16* p) {
  ushort8 u = *reinterpret_cast<const ushort8*>(p);
  return __builtin_bit_cast(bf16x8, u);
}
__global__ __launch_bounds__(256) void attn_fwd_v1(
    const float* __restrict__ Q, const float* __restrict__ K,
    const float* __restrict__ V, const int* __restrict__ M,
    float* __restrict__ O) {
  __shared__ __align__(16) u16 Klds[32 * KST];
  __shared__ __align__(16) u16 Vlds[64 * VST];
  __shared__ __align__(16) u16 Plds[4 * 16 * PST];
  const int tid = threadIdx.x, lane = tid & 63, wid = tid >> 6;
  const int lrow = lane & 15, lgrp = lane >> 4;
  const int bh = blockIdx.y, b = bh >> 4;
  const int q0 = blockIdx.x * 64 + wid * 16;
  const int base = bh * S_LEN * D_DIM, mbase = b * S_LEN * S_LEN;
  bf16x8 qf[2];
#pragma unroll
  for (int c = 0; c < 2; ++c) {
    const float* src = Q + base + (q0 + lrow) * 64 + c * 32 + lgrp * 8;
    float4 x = *reinterpret_cast<const float4*>(src);
    float4 y = *reinterpret_cast<const float4*>(src + 4);
    ushort8 u;
    u[0]=f2bf(x.x*0.125f); u[1]=f2bf(x.y*0.125f); u[2]=f2bf(x.z*0.125f); u[3]=f2bf(x.w*0.125f);
    u[4]=f2bf(y.x*0.125f); u[5]=f2bf(y.y*0.125f); u[6]=f2bf(y.z*0.125f); u[7]=f2bf(y.w*0.125f);
    qf[c] = __builtin_bit_cast(bf16x8, u);
  }
  f32x4 accO[4];
#pragma unroll
  for (int c = 0; c < 4; ++c) accO[c] = (f32x4){0.f,0.f,0.f,0.f};
  float m_[4] = {-1e9f,-1e9f,-1e9f,-1e9f}, l_[4] = {0.f,0.f,0.f,0.f};
  const int srow = tid >> 3, scol = (tid & 7) * 8;
  for (int kv0 = 0; kv0 < S_LEN; kv0 += 32) {
    __syncthreads();
    {
      const float* src = K + base + (kv0 + srow) * 64 + scol;
      float4 x = *reinterpret_cast<const float4*>(src);
      float4 y = *reinterpret_cast<const float4*>(src + 4);
      ushort8 u;
      u[0]=f2bf(x.x); u[1]=f2bf(x.y); u[2]=f2bf(x.z); u[3]=f2bf(x.w);
      u[4]=f2bf(y.x); u[5]=f2bf(y.y); u[6]=f2bf(y.z); u[7]=f2bf(y.w);
      *reinterpret_cast<ushort8*>(&Klds[srow * KST + scol]) = u;
    }
    {
      const float* src = V + base + (kv0 + srow) * 64 + scol;
      float4 x = *reinterpret_cast<const float4*>(src);
      float4 y = *reinterpret_cast<const float4*>(src + 4);
      float vals[8] = {x.x,x.y,x.z,x.w,y.x,y.y,y.z,y.w};
#pragma unroll
      for (int i = 0; i < 8; ++i) Vlds[(scol + i) * VST + srow] = f2bf(vals[i]);
    }
    __syncthreads();
    f32x4 s0 = (f32x4){0.f,0.f,0.f,0.f}, s1 = (f32x4){0.f,0.f,0.f,0.f};
#pragma unroll
    for (int c = 0; c < 2; ++c) {
      bf16x8 k0 = ld_frag(&Klds[lrow * KST + c * 32 + lgrp * 8]);
      bf16x8 k1 = ld_frag(&Klds[(16 + lrow) * KST + c * 32 + lgrp * 8]);
      s0 = __builtin_amdgcn_mfma_f32_16x16x32_bf16(qf[c], k0, s0, 0, 0, 0);
      s1 = __builtin_amdgcn_mfma_f32_16x16x32_bf16(qf[c], k1, s1, 0, 0, 0);
    }
#pragma unroll
    for (int r = 0; r < 4; ++r) {
      const int moff = mbase + (q0 + lgrp * 4 + r) * S_LEN + kv0 + lrow;
      if (M[moff] == 0)      s0[r] = -1e30f;
      if (M[moff + 16] == 0) s1[r] = -1e30f;
    }
    const int pbase = wid * 16 * PST;
#pragma unroll
    for (int r = 0; r < 4; ++r) {
      float t = fmaxf(s0[r], s1[r]);
      t = fmaxf(t, __shfl_xor(t, 1)); t = fmaxf(t, __shfl_xor(t, 2));
      t = fmaxf(t, __shfl_xor(t, 4)); t = fmaxf(t, __shfl_xor(t, 8));
      float mn = fmaxf(m_[r], t);
      float sf = __expf(m_[r] - mn);
      m_[r] = mn;
      float p0 = __expf(s0[r] - mn), p1 = __expf(s1[r] - mn);
      float su = p0 + p1;
      su += __shfl_xor(su, 1); su += __shfl_xor(su, 2);
      su += __shfl_xor(su, 4); su += __shfl_xor(su, 8);
      l_[r] = l_[r] * sf + su;
      accO[0][r] *= sf; accO[1][r] *= sf; accO[2][r] *= sf; accO[3][r] *= sf;
      const int prow = lgrp * 4 + r;
      Plds[pbase + prow * PST + lrow]      = f2bf(p0);
      Plds[pbase + prow * PST + 16 + lrow] = f2bf(p1);
    }
    asm volatile("s_waitcnt lgkmcnt(0)" ::: "memory");
    __builtin_amdgcn_sched_barrier(0);
    bf16x8 pa = ld_frag(&Plds[pbase + lrow * PST + lgrp * 8]);
#pragma unroll
    for (int c = 0; c < 4; ++c) {
      bf16x8 bv = ld_frag(&Vlds[(c * 16 + lrow) * VST + lgrp * 8]);
      accO[c] = __builtin_amdgcn_mfma_f32_16x16x32_bf16(pa, bv, accO[c], 0, 0, 0);
    }
  }
#pragma unroll
  for (int r = 0; r < 4; ++r) {
    const float inv = 1.0f / l_[r];
    float* dst = O + base + (q0 + lgrp * 4 + r) * 64;
#pragma unroll
    for (int c = 0; c < 4; ++c) dst[c * 16 + lrow] = accO[c][r] * inv;
  }
}

extern "C" void kernel_launch(void* const* d_in, const int* in_sizes, int n_in,
                              void* d_out, int out_size, void* d_ws, size_t ws_size,
                              hipStream_t stream) {
  const float* q = (const float*)d_in[0];
  const float* k = (const float*)d_in[1];
  const float* v = (const float*)d_in[2];
  const int*   m = (const int*)d_in[3];
  float* out = (float*)d_out;

  if (ws_size < (size_t)WS_NEED) {
    dim3 grid(S_LEN / 64, NBH);
    attn_fwd_v1<<<grid, dim3(256), 0, stream>>>(q, k, v, m, out);
    return;
  }

  u16* Kf = (u16*)((char*)d_ws + KF_OFF);
  u16* Vf = (u16*)((char*)d_ws + VF_OFF);
  u64* Mb = (u64*)((char*)d_ws + MB_OFF);

  prep_all<<<dim3(34816), dim3(256), 0, stream>>>(k, v, m, Kf, Vf, Mb);
  attn_fwd10<<<dim3(S_LEN / 128, NBH), dim3(512), 0, stream>>>(q, Kf, Vf, Mb, out);
}

// Round 11
// 84.319 us; speedup vs baseline: 1.0119x; 1.0119x over previous
//
#include <hip/hip_runtime.h>
#include <hip/hip_bf16.h>

typedef unsigned short u16;
typedef unsigned int   u32;
typedef unsigned long long u64;
typedef __attribute__((ext_vector_type(8)))  __bf16 bf16x8;
typedef __attribute__((ext_vector_type(4)))  float  f32x4;
typedef __attribute__((ext_vector_type(16))) float  f32x16;
typedef __attribute__((ext_vector_type(8)))  u16    ushort8;
typedef __attribute__((ext_vector_type(4)))  u32    u32x4;

#define S_LEN 2048
#define D_DIM 64
#define NBH   32
#define SD    131072
#define MROW  32
#define MB_PB 65536
#define NT    32            // KV tiles of 64

// Fragment-linear buffers: per (bh, tile): 512 frags x 16B = 8KB.
#define FR_BH 131072        // u16 per bh (32 tiles * 4096)

// workspace layout (bytes): Kf 8MB | Vf 8MB | Mb 1MB | pad
#define KF_OFF 0u
#define VF_OFF 8388608u
#define MB_OFF 16777216u
#define WS_NEED 17833984u

#define QSCALE 0.18033688011112042f   // 0.125 * log2(e) -> scores in log2 domain

static __device__ __forceinline__ u16 f2bf(float f) {
  u32 u = __builtin_bit_cast(u32, f);
  u += 0x7fffu + ((u >> 16) & 1u);
  return (u16)(u >> 16);
}

static __device__ __forceinline__ void gl16(const void* g, void* l) {
  __builtin_amdgcn_global_load_lds(
      (const __attribute__((address_space(1))) u32*)g,
      (__attribute__((address_space(3))) u32*)l, 16, 0, 0);
}

static __device__ __forceinline__ u32 cvtpk(float lo, float hi) {
  u32 d;
  asm("v_cvt_pk_bf16_f32 %0, %1, %2" : "=v"(d) : "v"(lo), "v"(hi));
  return d;
}
// ONLY safe when a and b are distinct SSA values (regalloc may alias equal
// values to one VGPR -> in-place half-swap). Equal-value exchange: __shfl_xor.
static __device__ __forceinline__ void plswap(u32& a, u32& b) {
  asm volatile("v_permlane32_swap_b32 %0, %1" : "+v"(a), "+v"(b));
}

#define WAITV0 asm volatile("s_waitcnt vmcnt(0)" ::: "memory")

// ---------------- fused prep kernel ----------------
__global__ __launch_bounds__(256) void prep_all(
    const float* __restrict__ K, const float* __restrict__ V, const int* __restrict__ M,
    u16* __restrict__ Kf, u16* __restrict__ Vf, u64* __restrict__ Mb) {
  const int bx = blockIdx.x, tid = threadIdx.x;
  if (bx < 2048) {
    __shared__ u16 t[64][72];
    const bool isK = bx < 1024;
    const int idx = isK ? bx : bx - 1024;
    const int bh = idx >> 5, tt = idx & 31;
    const float* src = (isK ? K : V) + ((size_t)bh * S_LEN + tt * 64) * D_DIM;
    const int r = tid >> 2, c0 = (tid & 3) * 16;
#pragma unroll
    for (int i = 0; i < 16; i += 4) {
      float4 x = *reinterpret_cast<const float4*>(src + r * 64 + c0 + i);
      t[r][c0+i]   = f2bf(x.x); t[r][c0+i+1] = f2bf(x.y);
      t[r][c0+i+2] = f2bf(x.z); t[r][c0+i+3] = f2bf(x.w);
    }
    __syncthreads();
    u16* dst = (isK ? Kf : Vf) + (size_t)bh * FR_BH + (size_t)tt * 4096;
#pragma unroll
    for (int qq = 0; qq < 2; ++qq) {
      const int f = tid * 2 + qq;
      const int sp = f >> 7, half = (f >> 6) & 1, l = f & 63;
      ushort8 u;
      if (isK) {
        u = *reinterpret_cast<const ushort8*>(&t[half * 32 + (l & 31)][sp * 16 + (l >> 5) * 8]);
      } else {
        const int kv0 = sp * 16 + (l >> 5) * 8, d = half * 32 + (l & 31);
#pragma unroll
        for (int j = 0; j < 8; ++j) u[j] = t[kv0 + j][d];
      }
      *reinterpret_cast<ushort8*>(dst + (size_t)f * 8) = u;
    }
  } else {
    int g = (bx - 2048) * 256 + tid;
    int lane = g & 63;
    int v = M[(size_t)g];
    u64 bits = __ballot(v != 0);
    if (lane == 0) Mb[g >> 6] = bits;
  }
}

// ---------------- main kernel (v11): v10 structure, launch-bounds fix ----------------
// 512 thr = 8 waves = 4 q-positions x 2 KV-half groups; no-max softmax partials
// are ADDITIVE -> LDS merge. __launch_bounds__(512,2): hipcc's 2nd arg behaves
// as min BLOCKS/CU (observed: (512,4) capped VGPR at 64 = 512-file/8-waves ->
// 12MB scratch spills). (512,2) -> 16 waves/CU cap -> 128 VGPR, no spills.
static __device__ __forceinline__ void iter_body(
    const u16* kb, const u16* vb, u64 mw,
    const bf16x8* Qf, f32x16& accOT0, f32x16& accOT1, float& l_,
    int lane, int hi) {
  const u32 mlo = (u32)mw, mhiw = (u32)(mw >> 32);

  // ---- QK^T (swapped): sT = K[tile] x Q^T, D[kv][q] ----
  f32x16 sT0 = {0,0,0,0,0,0,0,0,0,0,0,0,0,0,0,0};
  f32x16 sT1 = {0,0,0,0,0,0,0,0,0,0,0,0,0,0,0,0};
  __builtin_amdgcn_s_setprio(1);
#pragma unroll
  for (int s = 0; s < 4; ++s) {
    bf16x8 k0 = *reinterpret_cast<const bf16x8*>(kb + s * 1024 + lane * 8);
    bf16x8 k1 = *reinterpret_cast<const bf16x8*>(kb + s * 1024 + 512 + lane * 8);
    sT0 = __builtin_amdgcn_mfma_f32_32x32x16_bf16(k0, Qf[s], sT0, 0, 0, 0);
    sT1 = __builtin_amdgcn_mfma_f32_32x32x16_bf16(k1, Qf[s], sT1, 0, 0, 0);
  }
  __builtin_amdgcn_s_setprio(0);

  // ---- p = exp2(s), mask via sbfe+and, sum, pack to bf16 ----
  float lp0 = 0.f, lp1 = 0.f;
  u32 A0_[8], A1_[8];
#pragma unroll
  for (int T = 0; T < 2; ++T) {
    const f32x16& sv = T ? sT1 : sT0;
    const u32 mword = T ? mhiw : mlo;
#pragma unroll
    for (int j = 0; j < 8; ++j) {
      const int r0 = 2 * j, r1 = 2 * j + 1;
      const int b0 = (r0 & 3) + 8 * (r0 >> 2) + 4 * hi;
      const int b1 = (r1 & 3) + 8 * (r1 >> 2) + 4 * hi;
      float e0 = __builtin_amdgcn_exp2f(sv[r0]);
      float e1 = __builtin_amdgcn_exp2f(sv[r1]);
      int s0 = __builtin_amdgcn_sbfe(mword, b0, 1);
      int s1 = __builtin_amdgcn_sbfe(mword, b1, 1);
      e0 = __builtin_bit_cast(float, __builtin_bit_cast(u32, e0) & (u32)s0);
      e1 = __builtin_bit_cast(float, __builtin_bit_cast(u32, e1) & (u32)s1);
      lp0 += e0; lp1 += e1;
      u32 w = cvtpk(e0, e1);
      if (T == 0) A0_[j] = w; else A1_[j] = w;
    }
  }
  l_ += lp0 + lp1;

  // ---- build PV B-fragments in-register (distinct-operand permlane swaps) ----
  bf16x8 PA[4];
  {
    u32 a, c, b2, d2;
    a = A0_[0]; c = A0_[2]; plswap(a, c);
    b2 = A0_[1]; d2 = A0_[3]; plswap(b2, d2);
    u32x4 w0 = {a, b2, c, d2}; PA[0] = __builtin_bit_cast(bf16x8, w0);
    a = A0_[4]; c = A0_[6]; plswap(a, c);
    b2 = A0_[5]; d2 = A0_[7]; plswap(b2, d2);
    u32x4 w1 = {a, b2, c, d2}; PA[1] = __builtin_bit_cast(bf16x8, w1);
    a = A1_[0]; c = A1_[2]; plswap(a, c);
    b2 = A1_[1]; d2 = A1_[3]; plswap(b2, d2);
    u32x4 w2 = {a, b2, c, d2}; PA[2] = __builtin_bit_cast(bf16x8, w2);
    a = A1_[4]; c = A1_[6]; plswap(a, c);
    b2 = A1_[5]; d2 = A1_[7]; plswap(b2, d2);
    u32x4 w3 = {a, b2, c, d2}; PA[3] = __builtin_bit_cast(bf16x8, w3);
  }

  // ---- PV (swapped): accOT[D0] += V^T[D0-tile] x P^T ----
  __builtin_amdgcn_s_setprio(1);
#pragma unroll
  for (int ks = 0; ks < 4; ++ks) {
    bf16x8 v0 = *reinterpret_cast<const bf16x8*>(vb + ks * 1024 + lane * 8);
    bf16x8 v1 = *reinterpret_cast<const bf16x8*>(vb + ks * 1024 + 512 + lane * 8);
    accOT0 = __builtin_amdgcn_mfma_f32_32x32x16_bf16(v0, PA[ks], accOT0, 0, 0, 0);
    accOT1 = __builtin_amdgcn_mfma_f32_32x32x16_bf16(v1, PA[ks], accOT1, 0, 0, 0);
  }
  __builtin_amdgcn_s_setprio(0);
}

__global__ __launch_bounds__(512, 2) void attn_fwd11(
    const float* __restrict__ Q, const u16* __restrict__ Kf,
    const u16* __restrict__ Vf, const u64* __restrict__ Mb,
    float* __restrict__ O) {
  __shared__ __align__(16) u16 LB[32768];   // 64KB: per group 16384 u16 (K 2x4096 | V 2x4096)

  const int tid  = threadIdx.x;
  const int lane = tid & 63;
  const int wid  = tid >> 6;       // 0..7
  const int grp  = wid >> 2;       // KV-half group
  const int gw   = wid & 3;        // q-position within block
  const int l31  = lane & 31;
  const int hi   = lane >> 5;
  const int ts   = tid & 255;      // thread index within group

  const int bh = blockIdx.y, b = bh >> 4;
  const int q0w = blockIdx.x * 128 + gw * 32;
  const size_t base = (size_t)bh * SD;

  // Q fragments: f32 load + scale + pack (both groups load same rows)
  bf16x8 Qf[4];
  {
    const float* qsrc = Q + base + (size_t)(q0w + l31) * 64;
#pragma unroll
    for (int s = 0; s < 4; ++s) {
      const int d0 = s * 16 + hi * 8;
      float4 x = *reinterpret_cast<const float4*>(qsrc + d0);
      float4 y = *reinterpret_cast<const float4*>(qsrc + d0 + 4);
      u32x4 w;
      w[0] = cvtpk(x.x * QSCALE, x.y * QSCALE);
      w[1] = cvtpk(x.z * QSCALE, x.w * QSCALE);
      w[2] = cvtpk(y.x * QSCALE, y.y * QSCALE);
      w[3] = cvtpk(y.z * QSCALE, y.w * QSCALE);
      Qf[s] = __builtin_bit_cast(bf16x8, w);
    }
  }

  u16* gK = LB + grp * 16384;          // group K bufs [2][4096] u16
  u16* gV = gK + 8192;                 // group V bufs [2][4096] u16

  const u16* kfA = Kf + (size_t)bh * FR_BH;
  const u16* vfA = Vf + (size_t)bh * FR_BH;
  const u64* mp  = Mb + (size_t)b * MB_PB + (size_t)(q0w + l31) * MROW;

  f32x16 accOT0 = {0,0,0,0,0,0,0,0,0,0,0,0,0,0,0,0};
  f32x16 accOT1 = {0,0,0,0,0,0,0,0,0,0,0,0,0,0,0,0};
  float l_ = 0.f;

#define STAGE(buf, tile) do {                                                      \
    gl16(kfA + (size_t)(tile) * 4096 + ts * 8,        gK + (buf) * 4096 + ts * 8); \
    gl16(kfA + (size_t)(tile) * 4096 + 2048 + ts * 8, gK + (buf) * 4096 + 2048 + ts * 8); \
    gl16(vfA + (size_t)(tile) * 4096 + ts * 8,        gV + (buf) * 4096 + ts * 8); \
    gl16(vfA + (size_t)(tile) * 4096 + 2048 + ts * 8, gV + (buf) * 4096 + 2048 + ts * 8); \
  } while (0)

  const int t0 = grp * 16;
  STAGE(0, t0);
  u64 cmCur = mp[t0];
  WAITV0;
  __builtin_amdgcn_s_barrier();

  int buf = 0;
#pragma unroll 1
  for (int it = 0; it < 16; ++it) {
    u64 cmNext = 0;
    if (it < 15) {                       // prefetch next tile into other buffer
      STAGE(buf ^ 1, t0 + it + 1);
      cmNext = mp[t0 + it + 1];
    }
    iter_body(gK + buf * 4096, gV + buf * 4096, cmCur,
              Qf, accOT0, accOT1, l_, lane, hi);
    cmCur = cmNext;
    WAITV0;                              // own-wave stage loads landed under compute
    __builtin_amdgcn_s_barrier();        // all waves done: buffers swappable
    buf ^= 1;
  }

  // ---- merge the two KV-half partials (pure sums: no-max softmax is additive) ----
  l_ += __shfl_xor(l_, 32);
  __syncthreads();
  float* P = (float*)((char*)LB + 24576);          // [256 threads][34] f32
  const int pidx = (gw * 64 + lane) * 34;
  if (grp == 1) {
#pragma unroll
    for (int r = 0; r < 16; ++r) P[pidx + r]      = accOT0[r];
#pragma unroll
    for (int r = 0; r < 16; ++r) P[pidx + 16 + r] = accOT1[r];
    P[pidx + 32] = l_;
  }
  __syncthreads();
  if (grp == 0) {
#pragma unroll
    for (int r = 0; r < 16; ++r) accOT0[r] += P[pidx + r];
#pragma unroll
    for (int r = 0; r < 16; ++r) accOT1[r] += P[pidx + 16 + r];
    l_ += P[pidx + 32];

    const float inv = __builtin_amdgcn_rcpf(l_);
    float* sc = (float*)((char*)LB + gw * 4608);   // per-wave [32][36] f32 bounce
#pragma unroll
    for (int D0 = 0; D0 < 2; ++D0) {
      const f32x16& acc = D0 ? accOT1 : accOT0;
#pragma unroll
      for (int r = 0; r < 16; ++r) {
        const int dloc = (r & 3) + 8 * (r >> 2) + 4 * hi;
        sc[l31 * 36 + dloc] = acc[r] * inv;
      }
      asm volatile("s_waitcnt lgkmcnt(0)" ::: "memory");
      __builtin_amdgcn_sched_barrier(0);
      const int qq = lane >> 1, off = (lane & 1) * 16;
#pragma unroll
      for (int j = 0; j < 4; ++j) {
        float4 x = *reinterpret_cast<const float4*>(&sc[qq * 36 + off + j * 4]);
        *reinterpret_cast<float4*>(O + base + (size_t)(q0w + qq) * 64 + D0 * 32 + off + j * 4) = x;
      }
      asm volatile("s_waitcnt lgkmcnt(0)" ::: "memory");
      __builtin_amdgcn_sched_barrier(0);
    }
  }
#undef STAGE
}

// ---------------- fallback (round-1 kernel, used if ws too small) ----------------
#define KST 72
#define VST 40
#define PST 40
static __device__ __forceinline__ bf16x8 ld_frag(const u16* p) {
  ushort8 u = *reinterpret_cast<const ushort8*>(p);
  return __builtin_bit_cast(bf16x8, u);
}
__global__ __launch_bounds__(256) void attn_fwd_v1(
    const float* __restrict__ Q, const float* __restrict__ K,
    const float* __restrict__ V, const int* __restrict__ M,
    float* __restrict__ O) {
  __shared__ __align__(16) u16 Klds[32 * KST];
  __shared__ __align__(16) u16 Vlds[64 * VST];
  __shared__ __align__(16) u16 Plds[4 * 16 * PST];
  const int tid = threadIdx.x, lane = tid & 63, wid = tid >> 6;
  const int lrow = lane & 15, lgrp = lane >> 4;
  const int bh = blockIdx.y, b = bh >> 4;
  const int q0 = blockIdx.x * 64 + wid * 16;
  const int base = bh * S_LEN * D_DIM, mbase = b * S_LEN * S_LEN;
  bf16x8 qf[2];
#pragma unroll
  for (int c = 0; c < 2; ++c) {
    const float* src = Q + base + (q0 + lrow) * 64 + c * 32 + lgrp * 8;
    float4 x = *reinterpret_cast<const float4*>(src);
    float4 y = *reinterpret_cast<const float4*>(src + 4);
    ushort8 u;
    u[0]=f2bf(x.x*0.125f); u[1]=f2bf(x.y*0.125f); u[2]=f2bf(x.z*0.125f); u[3]=f2bf(x.w*0.125f);
    u[4]=f2bf(y.x*0.125f); u[5]=f2bf(y.y*0.125f); u[6]=f2bf(y.z*0.125f); u[7]=f2bf(y.w*0.125f);
    qf[c] = __builtin_bit_cast(bf16x8, u);
  }
  f32x4 accO[4];
#pragma unroll
  for (int c = 0; c < 4; ++c) accO[c] = (f32x4){0.f,0.f,0.f,0.f};
  float m_[4] = {-1e9f,-1e9f,-1e9f,-1e9f}, l_[4] = {0.f,0.f,0.f,0.f};
  const int srow = tid >> 3, scol = (tid & 7) * 8;
  for (int kv0 = 0; kv0 < S_LEN; kv0 += 32) {
    __syncthreads();
    {
      const float* src = K + base + (kv0 + srow) * 64 + scol;
      float4 x = *reinterpret_cast<const float4*>(src);
      float4 y = *reinterpret_cast<const float4*>(src + 4);
      ushort8 u;
      u[0]=f2bf(x.x); u[1]=f2bf(x.y); u[2]=f2bf(x.z); u[3]=f2bf(x.w);
      u[4]=f2bf(y.x); u[5]=f2bf(y.y); u[6]=f2bf(y.z); u[7]=f2bf(y.w);
      *reinterpret_cast<ushort8*>(&Klds[srow * KST + scol]) = u;
    }
    {
      const float* src = V + base + (kv0 + srow) * 64 + scol;
      float4 x = *reinterpret_cast<const float4*>(src);
      float4 y = *reinterpret_cast<const float4*>(src + 4);
      float vals[8] = {x.x,x.y,x.z,x.w,y.x,y.y,y.z,y.w};
#pragma unroll
      for (int i = 0; i < 8; ++i) Vlds[(scol + i) * VST + srow] = f2bf(vals[i]);
    }
    __syncthreads();
    f32x4 s0 = (f32x4){0.f,0.f,0.f,0.f}, s1 = (f32x4){0.f,0.f,0.f,0.f};
#pragma unroll
    for (int c = 0; c < 2; ++c) {
      bf16x8 k0 = ld_frag(&Klds[lrow * KST + c * 32 + lgrp * 8]);
      bf16x8 k1 = ld_frag(&Klds[(16 + lrow) * KST + c * 32 + lgrp * 8]);
      s0 = __builtin_amdgcn_mfma_f32_16x16x32_bf16(qf[c], k0, s0, 0, 0, 0);
      s1 = __builtin_amdgcn_mfma_f32_16x16x32_bf16(qf[c], k1, s1, 0, 0, 0);
    }
#pragma unroll
    for (int r = 0; r < 4; ++r) {
      const int moff = mbase + (q0 + lgrp * 4 + r) * S_LEN + kv0 + lrow;
      if (M[moff] == 0)      s0[r] = -1e30f;
      if (M[moff + 16] == 0) s1[r] = -1e30f;
    }
    const int pbase = wid * 16 * PST;
#pragma unroll
    for (int r = 0; r < 4; ++r) {
      float t = fmaxf(s0[r], s1[r]);
      t = fmaxf(t, __shfl_xor(t, 1)); t = fmaxf(t, __shfl_xor(t, 2));
      t = fmaxf(t, __shfl_xor(t, 4)); t = fmaxf(t, __shfl_xor(t, 8));
      float mn = fmaxf(m_[r], t);
      float sf = __expf(m_[r] - mn);
      m_[r] = mn;
      float p0 = __expf(s0[r] - mn), p1 = __expf(s1[r] - mn);
      float su = p0 + p1;
      su += __shfl_xor(su, 1); su += __shfl_xor(su, 2);
      su += __shfl_xor(su, 4); su += __shfl_xor(su, 8);
      l_[r] = l_[r] * sf + su;
      accO[0][r] *= sf; accO[1][r] *= sf; accO[2][r] *= sf; accO[3][r] *= sf;
      const int prow = lgrp * 4 + r;
      Plds[pbase + prow * PST + lrow]      = f2bf(p0);
      Plds[pbase + prow * PST + 16 + lrow] = f2bf(p1);
    }
    asm volatile("s_waitcnt lgkmcnt(0)" ::: "memory");
    __builtin_amdgcn_sched_barrier(0);
    bf16x8 pa = ld_frag(&Plds[pbase + lrow * PST + lgrp * 8]);
#pragma unroll
    for (int c = 0; c < 4; ++c) {
      bf16x8 bv = ld_frag(&Vlds[(c * 16 + lrow) * VST + lgrp * 8]);
      accO[c] = __builtin_amdgcn_mfma_f32_16x16x32_bf16(pa, bv, accO[c], 0, 0, 0);
    }
  }
#pragma unroll
  for (int r = 0; r < 4; ++r) {
    const float inv = 1.0f / l_[r];
    float* dst = O + base + (q0 + lgrp * 4 + r) * 64;
#pragma unroll
    for (int c = 0; c < 4; ++c) dst[c * 16 + lrow] = accO[c][r] * inv;
  }
}

extern "C" void kernel_launch(void* const* d_in, const int* in_sizes, int n_in,
                              void* d_out, int out_size, void* d_ws, size_t ws_size,
                              hipStream_t stream) {
  const float* q = (const float*)d_in[0];
  const float* k = (const float*)d_in[1];
  const float* v = (const float*)d_in[2];
  const int*   m = (const int*)d_in[3];
  float* out = (float*)d_out;

  if (ws_size < (size_t)WS_NEED) {
    dim3 grid(S_LEN / 64, NBH);
    attn_fwd_v1<<<grid, dim3(256), 0, stream>>>(q, k, v, m, out);
    return;
  }

  u16* Kf = (u16*)((char*)d_ws + KF_OFF);
  u16* Vf = (u16*)((char*)d_ws + VF_OFF);
  u64* Mb = (u64*)((char*)d_ws + MB_OFF);

  prep_all<<<dim3(34816), dim3(256), 0, stream>>>(k, v, m, Kf, Vf, Mb);
  attn_fwd11<<<dim3(S_LEN / 128, NBH), dim3(512), 0, stream>>>(q, Kf, Vf, Mb, out);
}